// Round 1
// baseline (1233.075 us; speedup 1.0000x reference)
//
#include <hip/hip_runtime.h>
#include <math.h>

// Problem constants
#define TSEQ 2048
#define DIM  512
#define NB   8
#define BTOT 16384            // NB*TSEQ
#define SCALE 0.04419417382415922f   // 1/sqrt(512)

// GEMM tile params
#define BM 128
#define BN 128
#define BK 16
#define LDP (BM + 4)          // padded LDS leading dim (132 floats, 528B rows: 16B aligned)

// ---------------------------------------------------------------------------
// K0: Mmat[d][f] = sum_g lin_w[d][g] * W_v[g][f]   (512x512x512, tiny)
// ---------------------------------------------------------------------------
__global__ __launch_bounds__(256) void k_linwv(const float* __restrict__ lin_w,
                                               const float* __restrict__ Wv,
                                               float* __restrict__ Mmat) {
    int idx = blockIdx.x * 256 + threadIdx.x;   // 65536 threads
    int d   = idx >> 7;                         // 0..511
    int f4  = (idx & 127) << 2;                 // 0..508
    const float* lw = lin_w + (size_t)d * DIM;
    float4 acc = make_float4(0.f, 0.f, 0.f, 0.f);
    for (int g = 0; g < DIM; ++g) {
        float l = lw[g];
        float4 wv = *(const float4*)(Wv + (size_t)g * DIM + f4);
        acc.x = fmaf(l, wv.x, acc.x);
        acc.y = fmaf(l, wv.y, acc.y);
        acc.z = fmaf(l, wv.z, acc.z);
        acc.w = fmaf(l, wv.w, acc.w);
    }
    *(float4*)(Mmat + (size_t)d * DIM + f4) = acc;
}

// ---------------------------------------------------------------------------
// K1: gather embeddings + project Q, K, VL.
//   C[m][n] = sum_k E[m][k] * B[n][k],  E[m] = embed[x[m]]
//   n-segment 0 -> Wq -> Q, 1 -> Wk -> Km, 2 -> Mmat -> VL
// ---------------------------------------------------------------------------
__global__ __launch_bounds__(256) void k_qkv(const int* __restrict__ x,
                                             const float* __restrict__ embed,
                                             const float* __restrict__ Wq,
                                             const float* __restrict__ Wk,
                                             const float* __restrict__ Mmat,
                                             float* __restrict__ Q,
                                             float* __restrict__ Km,
                                             float* __restrict__ VL) {
    __shared__ float As[BK][LDP];
    __shared__ float Bs[BK][LDP];
    int tid = threadIdx.x;
    int m0  = blockIdx.x * BM;
    int nblk = blockIdx.y;            // 0..11
    int seg  = nblk >> 2;             // 0,1,2
    int n0   = (nblk & 3) * BN;       // 0..384 within segment
    const float* Bbase = (seg == 0) ? Wq : (seg == 1) ? Wk : Mmat;
    float* Obase = (seg == 0) ? Q : (seg == 1) ? Km : VL;

    int lr = tid >> 1;                // 0..127
    int lc = (tid & 1) * 8;           // 0 or 8
    int tok = x[m0 + lr];
    const float* Arow = embed + (size_t)tok * DIM;
    const float* Brow = Bbase + (size_t)(n0 + lr) * DIM;

    int tx = tid & 15, ty = tid >> 4;
    float acc[8][8];
#pragma unroll
    for (int i = 0; i < 8; ++i)
#pragma unroll
        for (int j = 0; j < 8; ++j) acc[i][j] = 0.f;

    for (int k0 = 0; k0 < DIM; k0 += BK) {
        float4 a0 = *(const float4*)(Arow + k0 + lc);
        float4 a1 = *(const float4*)(Arow + k0 + lc + 4);
        float4 b0 = *(const float4*)(Brow + k0 + lc);
        float4 b1 = *(const float4*)(Brow + k0 + lc + 4);
        __syncthreads();
        As[lc + 0][lr] = a0.x; As[lc + 1][lr] = a0.y; As[lc + 2][lr] = a0.z; As[lc + 3][lr] = a0.w;
        As[lc + 4][lr] = a1.x; As[lc + 5][lr] = a1.y; As[lc + 6][lr] = a1.z; As[lc + 7][lr] = a1.w;
        Bs[lc + 0][lr] = b0.x; Bs[lc + 1][lr] = b0.y; Bs[lc + 2][lr] = b0.z; Bs[lc + 3][lr] = b0.w;
        Bs[lc + 4][lr] = b1.x; Bs[lc + 5][lr] = b1.y; Bs[lc + 6][lr] = b1.z; Bs[lc + 7][lr] = b1.w;
        __syncthreads();
#pragma unroll
        for (int kc = 0; kc < BK; ++kc) {
            float a[8], bb[8];
            *(float4*)&a[0]  = *(const float4*)&As[kc][ty * 8];
            *(float4*)&a[4]  = *(const float4*)&As[kc][ty * 8 + 4];
            *(float4*)&bb[0] = *(const float4*)&Bs[kc][tx * 8];
            *(float4*)&bb[4] = *(const float4*)&Bs[kc][tx * 8 + 4];
#pragma unroll
            for (int i = 0; i < 8; ++i)
#pragma unroll
                for (int j = 0; j < 8; ++j)
                    acc[i][j] = fmaf(a[i], bb[j], acc[i][j]);
        }
    }
    int cbase = n0 + tx * 8;
#pragma unroll
    for (int i = 0; i < 8; ++i) {
        int gm = m0 + ty * 8 + i;
        float4 c0 = make_float4(acc[i][0], acc[i][1], acc[i][2], acc[i][3]);
        float4 c1 = make_float4(acc[i][4], acc[i][5], acc[i][6], acc[i][7]);
        *(float4*)(Obase + (size_t)gm * DIM + cbase)     = c0;
        *(float4*)(Obase + (size_t)gm * DIM + cbase + 4) = c1;
    }
}

// ---------------------------------------------------------------------------
// K2: scores S[b][i][j] = SCALE * sum_d Q[b,i,d]*K[b,j,d]
// ---------------------------------------------------------------------------
__global__ __launch_bounds__(256) void k_scores(const float* __restrict__ Q,
                                                const float* __restrict__ Km,
                                                float* __restrict__ S) {
    __shared__ float As[BK][LDP];
    __shared__ float Bs[BK][LDP];
    int tid = threadIdx.x;
    int b   = blockIdx.z;
    int m0  = blockIdx.x * BM;
    int n0  = blockIdx.y * BN;
    const float* A  = Q  + (size_t)b * TSEQ * DIM;
    const float* Bm = Km + (size_t)b * TSEQ * DIM;
    float* Sout = S + (size_t)b * TSEQ * TSEQ;

    int lr = tid >> 1;
    int lc = (tid & 1) * 8;
    const float* Arow = A  + (size_t)(m0 + lr) * DIM;
    const float* Brow = Bm + (size_t)(n0 + lr) * DIM;

    int tx = tid & 15, ty = tid >> 4;
    float acc[8][8];
#pragma unroll
    for (int i = 0; i < 8; ++i)
#pragma unroll
        for (int j = 0; j < 8; ++j) acc[i][j] = 0.f;

    for (int k0 = 0; k0 < DIM; k0 += BK) {
        float4 a0 = *(const float4*)(Arow + k0 + lc);
        float4 a1 = *(const float4*)(Arow + k0 + lc + 4);
        float4 b0 = *(const float4*)(Brow + k0 + lc);
        float4 b1 = *(const float4*)(Brow + k0 + lc + 4);
        __syncthreads();
        As[lc + 0][lr] = a0.x; As[lc + 1][lr] = a0.y; As[lc + 2][lr] = a0.z; As[lc + 3][lr] = a0.w;
        As[lc + 4][lr] = a1.x; As[lc + 5][lr] = a1.y; As[lc + 6][lr] = a1.z; As[lc + 7][lr] = a1.w;
        Bs[lc + 0][lr] = b0.x; Bs[lc + 1][lr] = b0.y; Bs[lc + 2][lr] = b0.z; Bs[lc + 3][lr] = b0.w;
        Bs[lc + 4][lr] = b1.x; Bs[lc + 5][lr] = b1.y; Bs[lc + 6][lr] = b1.z; Bs[lc + 7][lr] = b1.w;
        __syncthreads();
#pragma unroll
        for (int kc = 0; kc < BK; ++kc) {
            float a[8], bb[8];
            *(float4*)&a[0]  = *(const float4*)&As[kc][ty * 8];
            *(float4*)&a[4]  = *(const float4*)&As[kc][ty * 8 + 4];
            *(float4*)&bb[0] = *(const float4*)&Bs[kc][tx * 8];
            *(float4*)&bb[4] = *(const float4*)&Bs[kc][tx * 8 + 4];
#pragma unroll
            for (int i = 0; i < 8; ++i)
#pragma unroll
                for (int j = 0; j < 8; ++j)
                    acc[i][j] = fmaf(a[i], bb[j], acc[i][j]);
        }
    }
    int cbase = n0 + tx * 8;
#pragma unroll
    for (int i = 0; i < 8; ++i) {
        int gi = m0 + ty * 8 + i;
        float4 c0 = make_float4(acc[i][0] * SCALE, acc[i][1] * SCALE, acc[i][2] * SCALE, acc[i][3] * SCALE);
        float4 c1 = make_float4(acc[i][4] * SCALE, acc[i][5] * SCALE, acc[i][6] * SCALE, acc[i][7] * SCALE);
        *(float4*)(Sout + (size_t)gi * TSEQ + cbase)     = c0;
        *(float4*)(Sout + (size_t)gi * TSEQ + cbase + 4) = c1;
    }
}

// ---------------------------------------------------------------------------
// K3: per-row softmax stats: mrow = max_j S, lrow = sum_j exp(S - m)
// ---------------------------------------------------------------------------
__global__ __launch_bounds__(256) void k_softstat(const float* __restrict__ S,
                                                  float* __restrict__ mrow,
                                                  float* __restrict__ lrow) {
    int row = blockIdx.x;                    // 0..16383
    int tid = threadIdx.x;
    const float* r = S + (size_t)row * TSEQ;
    float4 v0 = *(const float4*)(r + tid * 8);
    float4 v1 = *(const float4*)(r + tid * 8 + 4);
    float mx = fmaxf(fmaxf(fmaxf(v0.x, v0.y), fmaxf(v0.z, v0.w)),
                     fmaxf(fmaxf(v1.x, v1.y), fmaxf(v1.z, v1.w)));
#pragma unroll
    for (int off = 32; off > 0; off >>= 1) mx = fmaxf(mx, __shfl_xor(mx, off));
    __shared__ float sm[4];
    __shared__ float sl[4];
    if ((tid & 63) == 0) sm[tid >> 6] = mx;
    __syncthreads();
    mx = fmaxf(fmaxf(sm[0], sm[1]), fmaxf(sm[2], sm[3]));
    float s = __expf(v0.x - mx) + __expf(v0.y - mx) + __expf(v0.z - mx) + __expf(v0.w - mx)
            + __expf(v1.x - mx) + __expf(v1.y - mx) + __expf(v1.z - mx) + __expf(v1.w - mx);
#pragma unroll
    for (int off = 32; off > 0; off >>= 1) s += __shfl_xor(s, off);
    if ((tid & 63) == 0) sl[tid >> 6] = s;
    __syncthreads();
    if (tid == 0) {
        mrow[row] = mx;
        lrow[row] = sl[0] + sl[1] + sl[2] + sl[3];
    }
}

// ---------------------------------------------------------------------------
// K4: Y[i][d] = (sum_j exp(S[i][j]-m_i) * VL[j][d]) / l_i + lin_b[d];
//     relu; partial-sum over i into accg[b][d]
// ---------------------------------------------------------------------------
__global__ __launch_bounds__(256) void k_pv(const float* __restrict__ S,
                                            const float* __restrict__ VL,
                                            const float* __restrict__ mrow,
                                            const float* __restrict__ lrow,
                                            const float* __restrict__ lin_b,
                                            float* __restrict__ accg) {
    __shared__ float As[BK][LDP];
    __shared__ float Bs[BK][LDP];
    __shared__ float red[BN];
    int tid = threadIdx.x;
    int b   = blockIdx.z;
    int m0  = blockIdx.x * BM;      // i tile
    int n0  = blockIdx.y * BN;      // d tile
    const float* A  = S  + (size_t)b * TSEQ * TSEQ;
    const float* Bm = VL + (size_t)b * TSEQ * DIM;

    int lr = tid >> 1;
    int lc = (tid & 1) * 8;
    float mr = mrow[b * TSEQ + m0 + lr];
    const float* Arow = A + (size_t)(m0 + lr) * TSEQ;
    int bj = tid >> 4;              // 0..15 (j within tile)
    int bc = (tid & 15) * 8;        // 0..120 (d within tile)

    int tx = tid & 15, ty = tid >> 4;
    float acc[8][8];
#pragma unroll
    for (int i = 0; i < 8; ++i)
#pragma unroll
        for (int j = 0; j < 8; ++j) acc[i][j] = 0.f;

    for (int k0 = 0; k0 < TSEQ; k0 += BK) {
        float4 a0 = *(const float4*)(Arow + k0 + lc);
        float4 a1 = *(const float4*)(Arow + k0 + lc + 4);
        const float* Bp = Bm + (size_t)(k0 + bj) * DIM + n0 + bc;
        float4 b0 = *(const float4*)(Bp);
        float4 b1 = *(const float4*)(Bp + 4);
        __syncthreads();
        As[lc + 0][lr] = __expf(a0.x - mr); As[lc + 1][lr] = __expf(a0.y - mr);
        As[lc + 2][lr] = __expf(a0.z - mr); As[lc + 3][lr] = __expf(a0.w - mr);
        As[lc + 4][lr] = __expf(a1.x - mr); As[lc + 5][lr] = __expf(a1.y - mr);
        As[lc + 6][lr] = __expf(a1.z - mr); As[lc + 7][lr] = __expf(a1.w - mr);
        *(float4*)&Bs[bj][bc]     = b0;
        *(float4*)&Bs[bj][bc + 4] = b1;
        __syncthreads();
#pragma unroll
        for (int kc = 0; kc < BK; ++kc) {
            float a[8], bb[8];
            *(float4*)&a[0]  = *(const float4*)&As[kc][ty * 8];
            *(float4*)&a[4]  = *(const float4*)&As[kc][ty * 8 + 4];
            *(float4*)&bb[0] = *(const float4*)&Bs[kc][tx * 8];
            *(float4*)&bb[4] = *(const float4*)&Bs[kc][tx * 8 + 4];
#pragma unroll
            for (int i = 0; i < 8; ++i)
#pragma unroll
                for (int j = 0; j < 8; ++j)
                    acc[i][j] = fmaf(a[i], bb[j], acc[i][j]);
        }
    }
    // epilogue: y = acc/l_i + lin_b ; relu ; reduce over the 128 i's of this block
    float linv[8];
#pragma unroll
    for (int i = 0; i < 8; ++i) linv[i] = 1.f / lrow[b * TSEQ + m0 + ty * 8 + i];
    if (tid < BN) red[tid] = 0.f;
    __syncthreads();
#pragma unroll
    for (int j = 0; j < 8; ++j) {
        float bias = lin_b[n0 + tx * 8 + j];
        float cs = 0.f;
#pragma unroll
        for (int i = 0; i < 8; ++i)
            cs += fmaxf(fmaf(acc[i][j], linv[i], bias), 0.f);
        atomicAdd(&red[tx * 8 + j], cs);
    }
    __syncthreads();
    if (tid < BN) atomicAdd(&accg[b * DIM + n0 + tid], red[tid]);
}

// ---------------------------------------------------------------------------
// K5: out[b] = sigmoid( (accg[b]/T) . clf_w + clf_b )
// ---------------------------------------------------------------------------
__global__ void k_final(const float* __restrict__ accg,
                        const float* __restrict__ clf_w,
                        const float* __restrict__ clf_b,
                        float* __restrict__ out) {
    int tid  = threadIdx.x;          // 512 threads
    int b    = tid >> 6;
    int lane = tid & 63;
    float s = 0.f;
    for (int d = lane; d < DIM; d += 64) s = fmaf(accg[b * DIM + d], clf_w[d], s);
#pragma unroll
    for (int off = 32; off > 0; off >>= 1) s += __shfl_xor(s, off);
    if (lane == 0) {
        float z = s * (1.0f / TSEQ) + clf_b[0];
        out[b] = 1.f / (1.f + __expf(-z));
    }
}

// ---------------------------------------------------------------------------
extern "C" void kernel_launch(void* const* d_in, const int* in_sizes, int n_in,
                              void* d_out, int out_size, void* d_ws, size_t ws_size,
                              hipStream_t stream) {
    const int*   x     = (const int*)d_in[0];
    const float* embed = (const float*)d_in[1];
    const float* Wq    = (const float*)d_in[2];
    const float* Wk    = (const float*)d_in[3];
    const float* Wv    = (const float*)d_in[4];
    const float* lin_w = (const float*)d_in[5];
    const float* lin_b = (const float*)d_in[6];
    const float* clf_w = (const float*)d_in[7];
    const float* clf_b = (const float*)d_in[8];
    float* out = (float*)d_out;

    float* ws   = (float*)d_ws;
    float* Q    = ws;                                   // 16384*512
    float* Km   = Q    + (size_t)BTOT * DIM;            // 16384*512
    float* VL   = Km   + (size_t)BTOT * DIM;            // 16384*512
    float* Mmat = VL   + (size_t)BTOT * DIM;            // 512*512
    float* S    = Mmat + (size_t)DIM * DIM;             // 8*2048*2048
    float* mrow = S    + (size_t)NB * TSEQ * TSEQ;      // 16384
    float* lrow = mrow + BTOT;                          // 16384
    float* accg = lrow + BTOT;                          // 8*512

    hipMemsetAsync(accg, 0, NB * DIM * sizeof(float), stream);
    k_linwv<<<256, 256, 0, stream>>>(lin_w, Wv, Mmat);
    k_qkv<<<dim3(BTOT / BM, 12), 256, 0, stream>>>(x, embed, Wq, Wk, Mmat, Q, Km, VL);
    k_scores<<<dim3(TSEQ / BM, TSEQ / BN, NB), 256, 0, stream>>>(Q, Km, S);
    k_softstat<<<NB * TSEQ, 256, 0, stream>>>(S, mrow, lrow);
    k_pv<<<dim3(TSEQ / BM, DIM / BN, NB), 256, 0, stream>>>(S, VL, mrow, lrow, lin_b, accg);
    k_final<<<1, 512, 0, stream>>>(accg, clf_w, clf_b, out);
}

// Round 2
// 456.905 us; speedup vs baseline: 2.6988x; 2.6988x over previous
//
#include <hip/hip_runtime.h>
#include <math.h>

#define TSEQ 2048
#define DIM  512
#define NB   8
#define BTOT 16384
#define SCALE 0.04419417382415922f

typedef __attribute__((ext_vector_type(8))) short bf16x8;
typedef __attribute__((ext_vector_type(4))) float f32x4;
typedef __attribute__((ext_vector_type(8))) unsigned short u16x8;
typedef __attribute__((ext_vector_type(4))) unsigned short u16x4;
typedef unsigned short ushort_t;

__device__ __forceinline__ unsigned short f2bf(float f) {
    unsigned u = __builtin_bit_cast(unsigned, f);
    u += 0x7FFFu + ((u >> 16) & 1u);
    return (unsigned short)(u >> 16);
}
__device__ __forceinline__ float bf2f(unsigned short h) {
    unsigned u = ((unsigned)h) << 16;
    return __builtin_bit_cast(float, u);
}

// ---------------------------------------------------------------------------
// P0: gather embedding rows, split to hi/lo bf16
// ---------------------------------------------------------------------------
__global__ __launch_bounds__(256) void k_split_embed(const int* __restrict__ x,
                                                     const float* __restrict__ embed,
                                                     ushort_t* __restrict__ Ehi,
                                                     ushort_t* __restrict__ Elo) {
    int idx = blockIdx.x * 256 + threadIdx.x;
    int row = idx >> 6;
    int c   = (idx & 63) << 3;
    int tok = x[row];
    const float* src = embed + (size_t)tok * DIM + c;
    float4 v0 = *(const float4*)src;
    float4 v1 = *(const float4*)(src + 4);
    float vv[8] = {v0.x, v0.y, v0.z, v0.w, v1.x, v1.y, v1.z, v1.w};
    u16x8 h, l;
#pragma unroll
    for (int i = 0; i < 8; ++i) {
        unsigned short hh = f2bf(vv[i]);
        h[i] = hh;
        l[i] = f2bf(vv[i] - bf2f(hh));
    }
    *(u16x8*)(Ehi + (size_t)row * DIM + c) = h;
    *(u16x8*)(Elo + (size_t)row * DIM + c) = l;
}

// ---------------------------------------------------------------------------
// P1: split Wq, Wk to hi/lo bf16
// ---------------------------------------------------------------------------
__global__ __launch_bounds__(256) void k_split_w(const float* __restrict__ Wq,
                                                 const float* __restrict__ Wk,
                                                 ushort_t* __restrict__ Wqhi, ushort_t* __restrict__ Wqlo,
                                                 ushort_t* __restrict__ Wkhi, ushort_t* __restrict__ Wklo) {
    int idx = blockIdx.x * 256 + threadIdx.x;   // 131072 threads
    int which = idx >> 16;
    int e = (idx & 65535) << 2;
    const float* src = which ? Wk : Wq;
    ushort_t* dh = which ? Wkhi : Wqhi;
    ushort_t* dl = which ? Wklo : Wqlo;
    float4 v = *(const float4*)(src + e);
    float vv[4] = {v.x, v.y, v.z, v.w};
    u16x4 h, l;
#pragma unroll
    for (int i = 0; i < 4; ++i) {
        unsigned short hh = f2bf(vv[i]);
        h[i] = hh;
        l[i] = f2bf(vv[i] - bf2f(hh));
    }
    *(u16x4*)(dh + e) = h;
    *(u16x4*)(dl + e) = l;
}

// ---------------------------------------------------------------------------
// P2: M = lin_w @ W_v (fp32), output split hi/lo bf16
// ---------------------------------------------------------------------------
__global__ __launch_bounds__(256) void k_linwv(const float* __restrict__ lin_w,
                                               const float* __restrict__ Wv,
                                               ushort_t* __restrict__ Mhi,
                                               ushort_t* __restrict__ Mlo) {
    int idx = blockIdx.x * 256 + threadIdx.x;
    int d   = idx >> 7;
    int f4  = (idx & 127) << 2;
    const float* lw = lin_w + (size_t)d * DIM;
    float4 acc = make_float4(0.f, 0.f, 0.f, 0.f);
    for (int g = 0; g < DIM; ++g) {
        float l = lw[g];
        float4 wv = *(const float4*)(Wv + (size_t)g * DIM + f4);
        acc.x = fmaf(l, wv.x, acc.x);
        acc.y = fmaf(l, wv.y, acc.y);
        acc.z = fmaf(l, wv.z, acc.z);
        acc.w = fmaf(l, wv.w, acc.w);
    }
    float vv[4] = {acc.x, acc.y, acc.z, acc.w};
    u16x4 h, l;
#pragma unroll
    for (int i = 0; i < 4; ++i) {
        unsigned short hh = f2bf(vv[i]);
        h[i] = hh;
        l[i] = f2bf(vv[i] - bf2f(hh));
    }
    *(u16x4*)(Mhi + (size_t)d * DIM + f4) = h;
    *(u16x4*)(Mlo + (size_t)d * DIM + f4) = l;
}

// ---------------------------------------------------------------------------
// K1: Q/K projection, 3-pass split-bf16 MFMA, outputs hi/lo bf16
//     grid (128, 8): y>>2 -> seg (0=Q,1=K), (y&3)*128 -> n0
// ---------------------------------------------------------------------------
__global__ __launch_bounds__(256) void k_proj_qk(const ushort_t* __restrict__ Ehi, const ushort_t* __restrict__ Elo,
                                                 const ushort_t* __restrict__ Wqhi, const ushort_t* __restrict__ Wqlo,
                                                 const ushort_t* __restrict__ Wkhi, const ushort_t* __restrict__ Wklo,
                                                 ushort_t* __restrict__ Qhi, ushort_t* __restrict__ Qlo,
                                                 ushort_t* __restrict__ Khi, ushort_t* __restrict__ Klo) {
    __shared__ ushort_t Ah[128][40], Al[128][40], Bh[128][40], Bl[128][40];
    int tid = threadIdx.x;
    int m0 = blockIdx.x * 128;
    int seg = blockIdx.y >> 2;
    int n0  = (blockIdx.y & 3) * 128;
    const ushort_t* Bgh = seg ? Wkhi : Wqhi;
    const ushort_t* Bgl = seg ? Wklo : Wqlo;
    ushort_t* Ohi = seg ? Khi : Qhi;
    ushort_t* Olo = seg ? Klo : Qlo;

    int wave = tid >> 6, lane = tid & 63;
    int wm = wave >> 1, wn = wave & 1;
    int q = lane >> 4, l16 = lane & 15;
    int r = tid >> 1, c0 = (tid & 1) << 4;

    const ushort_t* gah = Ehi + (size_t)(m0 + r) * DIM + c0;
    const ushort_t* gal = Elo + (size_t)(m0 + r) * DIM + c0;
    const ushort_t* gbh = Bgh + (size_t)(n0 + r) * DIM + c0;
    const ushort_t* gbl = Bgl + (size_t)(n0 + r) * DIM + c0;

    const f32x4 fz = {0.f, 0.f, 0.f, 0.f};
    f32x4 acc[4][4];
#pragma unroll
    for (int i = 0; i < 4; ++i)
#pragma unroll
        for (int j = 0; j < 4; ++j) acc[i][j] = fz;

    for (int k0 = 0; k0 < DIM; k0 += 32) {
        u16x8 a0 = *(const u16x8*)(gah + k0);
        u16x8 a1 = *(const u16x8*)(gah + k0 + 8);
        u16x8 a2 = *(const u16x8*)(gal + k0);
        u16x8 a3 = *(const u16x8*)(gal + k0 + 8);
        u16x8 b0 = *(const u16x8*)(gbh + k0);
        u16x8 b1 = *(const u16x8*)(gbh + k0 + 8);
        u16x8 b2 = *(const u16x8*)(gbl + k0);
        u16x8 b3 = *(const u16x8*)(gbl + k0 + 8);
        __syncthreads();
        *(u16x8*)&Ah[r][c0] = a0; *(u16x8*)&Ah[r][c0 + 8] = a1;
        *(u16x8*)&Al[r][c0] = a2; *(u16x8*)&Al[r][c0 + 8] = a3;
        *(u16x8*)&Bh[r][c0] = b0; *(u16x8*)&Bh[r][c0 + 8] = b1;
        *(u16x8*)&Bl[r][c0] = b2; *(u16x8*)&Bl[r][c0 + 8] = b3;
        __syncthreads();
        bf16x8 fah[4], fal[4], fbh[4], fbl[4];
#pragma unroll
        for (int t = 0; t < 4; ++t) {
            int ar = wm * 64 + t * 16 + l16;
            int br = wn * 64 + t * 16 + l16;
            fah[t] = *(const bf16x8*)&Ah[ar][q * 8];
            fal[t] = *(const bf16x8*)&Al[ar][q * 8];
            fbh[t] = *(const bf16x8*)&Bh[br][q * 8];
            fbl[t] = *(const bf16x8*)&Bl[br][q * 8];
        }
#pragma unroll
        for (int i = 0; i < 4; ++i)
#pragma unroll
            for (int j = 0; j < 4; ++j) {
                f32x4 c = acc[i][j];
                c = __builtin_amdgcn_mfma_f32_16x16x32_bf16(fal[i], fbh[j], c, 0, 0, 0);
                c = __builtin_amdgcn_mfma_f32_16x16x32_bf16(fah[i], fbl[j], c, 0, 0, 0);
                c = __builtin_amdgcn_mfma_f32_16x16x32_bf16(fah[i], fbh[j], c, 0, 0, 0);
                acc[i][j] = c;
            }
    }
#pragma unroll
    for (int i = 0; i < 4; ++i)
#pragma unroll
        for (int j = 0; j < 4; ++j) {
            int col = n0 + wn * 64 + j * 16 + l16;
            f32x4 c = acc[i][j];
#pragma unroll
            for (int rr = 0; rr < 4; ++rr) {
                int row = m0 + wm * 64 + i * 16 + q * 4 + rr;
                float v = c[rr];
                unsigned short hh = f2bf(v);
                Ohi[(size_t)row * DIM + col] = hh;
                Olo[(size_t)row * DIM + col] = f2bf(v - bf2f(hh));
            }
        }
}

// ---------------------------------------------------------------------------
// K2: VLT[d][t] = sum_f M[d][f] * E[t][f]  (3-pass), written d-major (transposed)
//     grid (4, 128): x -> d tile, y -> t tile
// ---------------------------------------------------------------------------
__global__ __launch_bounds__(256) void k_proj_vlt(const ushort_t* __restrict__ Mhi, const ushort_t* __restrict__ Mlo,
                                                  const ushort_t* __restrict__ Ehi, const ushort_t* __restrict__ Elo,
                                                  ushort_t* __restrict__ VLT) {
    __shared__ ushort_t Ah[128][40], Al[128][40], Bh[128][40], Bl[128][40];
    int tid = threadIdx.x;
    int m0 = blockIdx.x * 128;   // d
    int n0 = blockIdx.y * 128;   // t
    int wave = tid >> 6, lane = tid & 63;
    int wm = wave >> 1, wn = wave & 1;
    int q = lane >> 4, l16 = lane & 15;
    int r = tid >> 1, c0 = (tid & 1) << 4;

    const ushort_t* gah = Mhi + (size_t)(m0 + r) * DIM + c0;
    const ushort_t* gal = Mlo + (size_t)(m0 + r) * DIM + c0;
    const ushort_t* gbh = Ehi + (size_t)(n0 + r) * DIM + c0;
    const ushort_t* gbl = Elo + (size_t)(n0 + r) * DIM + c0;

    const f32x4 fz = {0.f, 0.f, 0.f, 0.f};
    f32x4 acc[4][4];
#pragma unroll
    for (int i = 0; i < 4; ++i)
#pragma unroll
        for (int j = 0; j < 4; ++j) acc[i][j] = fz;

    for (int k0 = 0; k0 < DIM; k0 += 32) {
        u16x8 a0 = *(const u16x8*)(gah + k0);
        u16x8 a1 = *(const u16x8*)(gah + k0 + 8);
        u16x8 a2 = *(const u16x8*)(gal + k0);
        u16x8 a3 = *(const u16x8*)(gal + k0 + 8);
        u16x8 b0 = *(const u16x8*)(gbh + k0);
        u16x8 b1 = *(const u16x8*)(gbh + k0 + 8);
        u16x8 b2 = *(const u16x8*)(gbl + k0);
        u16x8 b3 = *(const u16x8*)(gbl + k0 + 8);
        __syncthreads();
        *(u16x8*)&Ah[r][c0] = a0; *(u16x8*)&Ah[r][c0 + 8] = a1;
        *(u16x8*)&Al[r][c0] = a2; *(u16x8*)&Al[r][c0 + 8] = a3;
        *(u16x8*)&Bh[r][c0] = b0; *(u16x8*)&Bh[r][c0 + 8] = b1;
        *(u16x8*)&Bl[r][c0] = b2; *(u16x8*)&Bl[r][c0 + 8] = b3;
        __syncthreads();
        bf16x8 fah[4], fal[4], fbh[4], fbl[4];
#pragma unroll
        for (int t = 0; t < 4; ++t) {
            int ar = wm * 64 + t * 16 + l16;
            int br = wn * 64 + t * 16 + l16;
            fah[t] = *(const bf16x8*)&Ah[ar][q * 8];
            fal[t] = *(const bf16x8*)&Al[ar][q * 8];
            fbh[t] = *(const bf16x8*)&Bh[br][q * 8];
            fbl[t] = *(const bf16x8*)&Bl[br][q * 8];
        }
#pragma unroll
        for (int i = 0; i < 4; ++i)
#pragma unroll
            for (int j = 0; j < 4; ++j) {
                f32x4 c = acc[i][j];
                c = __builtin_amdgcn_mfma_f32_16x16x32_bf16(fal[i], fbh[j], c, 0, 0, 0);
                c = __builtin_amdgcn_mfma_f32_16x16x32_bf16(fah[i], fbl[j], c, 0, 0, 0);
                c = __builtin_amdgcn_mfma_f32_16x16x32_bf16(fah[i], fbh[j], c, 0, 0, 0);
                acc[i][j] = c;
            }
    }
#pragma unroll
    for (int i = 0; i < 4; ++i)
#pragma unroll
        for (int j = 0; j < 4; ++j) {
            int col = n0 + wn * 64 + j * 16 + l16;   // t
            f32x4 c = acc[i][j];
#pragma unroll
            for (int rr = 0; rr < 4; ++rr) {
                int row = m0 + wm * 64 + i * 16 + q * 4 + rr;   // d
                VLT[(size_t)row * BTOT + col] = f2bf(c[rr]);
            }
        }
}

// ---------------------------------------------------------------------------
// K3: scores S[b][i][j] = SCALE * q.k, 3-pass split-bf16 MFMA, fp32 out
// ---------------------------------------------------------------------------
__global__ __launch_bounds__(256) void k_scores(const ushort_t* __restrict__ Qhi, const ushort_t* __restrict__ Qlo,
                                                const ushort_t* __restrict__ Khi, const ushort_t* __restrict__ Klo,
                                                float* __restrict__ S) {
    __shared__ ushort_t Ah[128][40], Al[128][40], Bh[128][40], Bl[128][40];
    int tid = threadIdx.x;
    int b = blockIdx.z;
    int m0 = blockIdx.x * 128;
    int n0 = blockIdx.y * 128;
    int wave = tid >> 6, lane = tid & 63;
    int wm = wave >> 1, wn = wave & 1;
    int q = lane >> 4, l16 = lane & 15;
    int r = tid >> 1, c0 = (tid & 1) << 4;

    const ushort_t* gah = Qhi + ((size_t)b * TSEQ + m0 + r) * DIM + c0;
    const ushort_t* gal = Qlo + ((size_t)b * TSEQ + m0 + r) * DIM + c0;
    const ushort_t* gbh = Khi + ((size_t)b * TSEQ + n0 + r) * DIM + c0;
    const ushort_t* gbl = Klo + ((size_t)b * TSEQ + n0 + r) * DIM + c0;

    const f32x4 fz = {0.f, 0.f, 0.f, 0.f};
    f32x4 acc[4][4];
#pragma unroll
    for (int i = 0; i < 4; ++i)
#pragma unroll
        for (int j = 0; j < 4; ++j) acc[i][j] = fz;

    for (int k0 = 0; k0 < DIM; k0 += 32) {
        u16x8 a0 = *(const u16x8*)(gah + k0);
        u16x8 a1 = *(const u16x8*)(gah + k0 + 8);
        u16x8 a2 = *(const u16x8*)(gal + k0);
        u16x8 a3 = *(const u16x8*)(gal + k0 + 8);
        u16x8 b0 = *(const u16x8*)(gbh + k0);
        u16x8 b1 = *(const u16x8*)(gbh + k0 + 8);
        u16x8 b2 = *(const u16x8*)(gbl + k0);
        u16x8 b3 = *(const u16x8*)(gbl + k0 + 8);
        __syncthreads();
        *(u16x8*)&Ah[r][c0] = a0; *(u16x8*)&Ah[r][c0 + 8] = a1;
        *(u16x8*)&Al[r][c0] = a2; *(u16x8*)&Al[r][c0 + 8] = a3;
        *(u16x8*)&Bh[r][c0] = b0; *(u16x8*)&Bh[r][c0 + 8] = b1;
        *(u16x8*)&Bl[r][c0] = b2; *(u16x8*)&Bl[r][c0 + 8] = b3;
        __syncthreads();
        bf16x8 fah[4], fal[4], fbh[4], fbl[4];
#pragma unroll
        for (int t = 0; t < 4; ++t) {
            int ar = wm * 64 + t * 16 + l16;
            int br = wn * 64 + t * 16 + l16;
            fah[t] = *(const bf16x8*)&Ah[ar][q * 8];
            fal[t] = *(const bf16x8*)&Al[ar][q * 8];
            fbh[t] = *(const bf16x8*)&Bh[br][q * 8];
            fbl[t] = *(const bf16x8*)&Bl[br][q * 8];
        }
#pragma unroll
        for (int i = 0; i < 4; ++i)
#pragma unroll
            for (int j = 0; j < 4; ++j) {
                f32x4 c = acc[i][j];
                c = __builtin_amdgcn_mfma_f32_16x16x32_bf16(fal[i], fbh[j], c, 0, 0, 0);
                c = __builtin_amdgcn_mfma_f32_16x16x32_bf16(fah[i], fbl[j], c, 0, 0, 0);
                c = __builtin_amdgcn_mfma_f32_16x16x32_bf16(fah[i], fbh[j], c, 0, 0, 0);
                acc[i][j] = c;
            }
    }
    float* Sout = S + (size_t)b * TSEQ * TSEQ;
#pragma unroll
    for (int i = 0; i < 4; ++i)
#pragma unroll
        for (int j = 0; j < 4; ++j) {
            int col = n0 + wn * 64 + j * 16 + l16;
            f32x4 c = acc[i][j];
#pragma unroll
            for (int rr = 0; rr < 4; ++rr) {
                int row = m0 + wm * 64 + i * 16 + q * 4 + rr;
                Sout[(size_t)row * TSEQ + col] = c[rr] * SCALE;
            }
        }
}

// ---------------------------------------------------------------------------
// K4: per-row softmax stats
// ---------------------------------------------------------------------------
__global__ __launch_bounds__(256) void k_softstat(const float* __restrict__ S,
                                                  float* __restrict__ mrow,
                                                  float* __restrict__ lrow) {
    int row = blockIdx.x;
    int tid = threadIdx.x;
    const float* r = S + (size_t)row * TSEQ;
    float4 v0 = *(const float4*)(r + tid * 8);
    float4 v1 = *(const float4*)(r + tid * 8 + 4);
    float mx = fmaxf(fmaxf(fmaxf(v0.x, v0.y), fmaxf(v0.z, v0.w)),
                     fmaxf(fmaxf(v1.x, v1.y), fmaxf(v1.z, v1.w)));
#pragma unroll
    for (int off = 32; off > 0; off >>= 1) mx = fmaxf(mx, __shfl_xor(mx, off));
    __shared__ float sm[4];
    __shared__ float sl[4];
    if ((tid & 63) == 0) sm[tid >> 6] = mx;
    __syncthreads();
    mx = fmaxf(fmaxf(sm[0], sm[1]), fmaxf(sm[2], sm[3]));
    float s = __expf(v0.x - mx) + __expf(v0.y - mx) + __expf(v0.z - mx) + __expf(v0.w - mx)
            + __expf(v1.x - mx) + __expf(v1.y - mx) + __expf(v1.z - mx) + __expf(v1.w - mx);
#pragma unroll
    for (int off = 32; off > 0; off >>= 1) s += __shfl_xor(s, off);
    if ((tid & 63) == 0) sl[tid >> 6] = s;
    __syncthreads();
    if (tid == 0) {
        mrow[row] = mx;
        lrow[row] = sl[0] + sl[1] + sl[2] + sl[3];
    }
}

// ---------------------------------------------------------------------------
// K5: PV via single-pass bf16 MFMA. A = bf16(exp(S - m)) staged on the fly,
//     B = VLT. Epilogue: /l + bias, relu, reduce over i, atomicAdd to accg.
// ---------------------------------------------------------------------------
__global__ __launch_bounds__(256) void k_pv(const float* __restrict__ S,
                                            const ushort_t* __restrict__ VLT,
                                            const float* __restrict__ mrow,
                                            const float* __restrict__ lrow,
                                            const float* __restrict__ lin_b,
                                            float* __restrict__ accg) {
    __shared__ ushort_t As[128][40], Bs[128][40];
    __shared__ float linv_s[128], bias_s[128];
    int tid = threadIdx.x;
    int b  = blockIdx.z;
    int m0 = blockIdx.x * 128;   // i
    int n0 = blockIdx.y * 128;   // d
    if (tid < 128) {
        linv_s[tid] = 1.f / lrow[b * TSEQ + m0 + tid];
        bias_s[tid] = lin_b[n0 + tid];
    }
    int wave = tid >> 6, lane = tid & 63;
    int wm = wave >> 1, wn = wave & 1;
    int q = lane >> 4, l16 = lane & 15;
    int r = tid >> 1, c0 = (tid & 1) << 4;

    const float* sp = S + ((size_t)b * TSEQ + m0 + r) * TSEQ + c0;
    float mr = mrow[b * TSEQ + m0 + r];
    const ushort_t* gb = VLT + (size_t)(n0 + r) * BTOT + b * TSEQ + c0;

    const f32x4 fz = {0.f, 0.f, 0.f, 0.f};
    f32x4 acc[4][4];
#pragma unroll
    for (int i = 0; i < 4; ++i)
#pragma unroll
        for (int j = 0; j < 4; ++j) acc[i][j] = fz;

    for (int k0 = 0; k0 < TSEQ; k0 += 32) {
        float4 f0 = *(const float4*)(sp + k0);
        float4 f1 = *(const float4*)(sp + k0 + 4);
        float4 f2 = *(const float4*)(sp + k0 + 8);
        float4 f3 = *(const float4*)(sp + k0 + 12);
        u16x8 vb0 = *(const u16x8*)(gb + k0);
        u16x8 vb1 = *(const u16x8*)(gb + k0 + 8);
        float ff[16] = {f0.x, f0.y, f0.z, f0.w, f1.x, f1.y, f1.z, f1.w,
                        f2.x, f2.y, f2.z, f2.w, f3.x, f3.y, f3.z, f3.w};
        u16x8 p0, p1;
#pragma unroll
        for (int i = 0; i < 8; ++i) {
            p0[i] = f2bf(__expf(ff[i] - mr));
            p1[i] = f2bf(__expf(ff[8 + i] - mr));
        }
        __syncthreads();
        *(u16x8*)&As[r][c0] = p0; *(u16x8*)&As[r][c0 + 8] = p1;
        *(u16x8*)&Bs[r][c0] = vb0; *(u16x8*)&Bs[r][c0 + 8] = vb1;
        __syncthreads();
        bf16x8 fa[4], fb[4];
#pragma unroll
        for (int t = 0; t < 4; ++t) {
            int ar = wm * 64 + t * 16 + l16;
            int br = wn * 64 + t * 16 + l16;
            fa[t] = *(const bf16x8*)&As[ar][q * 8];
            fb[t] = *(const bf16x8*)&Bs[br][q * 8];
        }
#pragma unroll
        for (int i = 0; i < 4; ++i)
#pragma unroll
            for (int j = 0; j < 4; ++j)
                acc[i][j] = __builtin_amdgcn_mfma_f32_16x16x32_bf16(fa[i], fb[j], acc[i][j], 0, 0, 0);
    }
    float dsum[4] = {0.f, 0.f, 0.f, 0.f};
#pragma unroll
    for (int i = 0; i < 4; ++i)
#pragma unroll
        for (int j = 0; j < 4; ++j) {
            f32x4 c = acc[i][j];
            float bias = bias_s[wn * 64 + j * 16 + l16];
#pragma unroll
            for (int rr = 0; rr < 4; ++rr) {
                int ri = wm * 64 + i * 16 + q * 4 + rr;
                float v = fmaf(c[rr], linv_s[ri], bias);
                dsum[j] += fmaxf(v, 0.f);
            }
        }
#pragma unroll
    for (int j = 0; j < 4; ++j) {
        float v = dsum[j];
        v += __shfl_xor(v, 16);
        v += __shfl_xor(v, 32);
        if (q == 0) atomicAdd(&accg[b * DIM + n0 + wn * 64 + j * 16 + l16], v);
    }
}

// ---------------------------------------------------------------------------
// K6: out[b] = sigmoid((accg[b]/T) . clf_w + clf_b)
// ---------------------------------------------------------------------------
__global__ void k_final(const float* __restrict__ accg,
                        const float* __restrict__ clf_w,
                        const float* __restrict__ clf_b,
                        float* __restrict__ out) {
    int tid  = threadIdx.x;
    int b    = tid >> 6;
    int lane = tid & 63;
    float s = 0.f;
    for (int d = lane; d < DIM; d += 64) s = fmaf(accg[b * DIM + d], clf_w[d], s);
#pragma unroll
    for (int off = 32; off > 0; off >>= 1) s += __shfl_xor(s, off);
    if (lane == 0) {
        float z = s * (1.0f / TSEQ) + clf_b[0];
        out[b] = 1.f / (1.f + __expf(-z));
    }
}

// ---------------------------------------------------------------------------
extern "C" void kernel_launch(void* const* d_in, const int* in_sizes, int n_in,
                              void* d_out, int out_size, void* d_ws, size_t ws_size,
                              hipStream_t stream) {
    const int*   x     = (const int*)d_in[0];
    const float* embed = (const float*)d_in[1];
    const float* Wq    = (const float*)d_in[2];
    const float* Wk    = (const float*)d_in[3];
    const float* Wv    = (const float*)d_in[4];
    const float* lin_w = (const float*)d_in[5];
    const float* lin_b = (const float*)d_in[6];
    const float* clf_w = (const float*)d_in[7];
    const float* clf_b = (const float*)d_in[8];
    float* out = (float*)d_out;

    char* wsb = (char*)d_ws;
    // S occupies the first 134 MB; prep buffers alias its start (dead before S written)
    float*    S    = (float*)wsb;
    ushort_t* Ehi  = (ushort_t*)wsb;
    ushort_t* Elo  = Ehi  + (size_t)BTOT * DIM;
    ushort_t* Wqhi = Elo  + (size_t)BTOT * DIM;
    ushort_t* Wqlo = Wqhi + (size_t)DIM * DIM;
    ushort_t* Wkhi = Wqlo + (size_t)DIM * DIM;
    ushort_t* Wklo = Wkhi + (size_t)DIM * DIM;
    ushort_t* Mhi  = Wklo + (size_t)DIM * DIM;
    ushort_t* Mlo  = Mhi  + (size_t)DIM * DIM;
    // persistent region after S
    ushort_t* Qhi  = (ushort_t*)(wsb + (size_t)NB * TSEQ * TSEQ * 4);
    ushort_t* Qlo  = Qhi + (size_t)BTOT * DIM;
    ushort_t* Khi  = Qlo + (size_t)BTOT * DIM;
    ushort_t* Klo  = Khi + (size_t)BTOT * DIM;
    ushort_t* VLT  = Klo + (size_t)BTOT * DIM;
    float* mrow = (float*)(VLT + (size_t)BTOT * DIM);
    float* lrow = mrow + BTOT;
    float* accg = lrow + BTOT;

    hipMemsetAsync(accg, 0, NB * DIM * sizeof(float), stream);
    k_split_embed<<<BTOT * 64 / 256, 256, 0, stream>>>(x, embed, Ehi, Elo);
    k_split_w<<<512, 256, 0, stream>>>(Wq, Wk, Wqhi, Wqlo, Wkhi, Wklo);
    k_linwv<<<256, 256, 0, stream>>>(lin_w, Wv, Mhi, Mlo);
    k_proj_qk<<<dim3(128, 8), 256, 0, stream>>>(Ehi, Elo, Wqhi, Wqlo, Wkhi, Wklo, Qhi, Qlo, Khi, Klo);
    k_proj_vlt<<<dim3(4, 128), 256, 0, stream>>>(Mhi, Mlo, Ehi, Elo, VLT);
    k_scores<<<dim3(16, 16, 8), 256, 0, stream>>>(Qhi, Qlo, Khi, Klo, S);
    k_softstat<<<BTOT, 256, 0, stream>>>(S, mrow, lrow);
    k_pv<<<dim3(16, 4, 8), 256, 0, stream>>>(S, VLT, mrow, lrow, lin_b, accg);
    k_final<<<1, 512, 0, stream>>>(accg, clf_w, clf_b, out);
}